// Round 15
// baseline (410.077 us; speedup 1.0000x reference)
//
#include <hip/hip_runtime.h>

typedef unsigned short u16;
typedef unsigned int   u32;
typedef __attribute__((ext_vector_type(8))) short short8;
typedef __attribute__((ext_vector_type(4))) short short4_t;
typedef __attribute__((ext_vector_type(4))) float f32x4;

__device__ __forceinline__ float bf2f(u16 v) {
  return __uint_as_float(((u32)v) << 16);
}
__device__ __forceinline__ u16 f2bf(float f) {
  u32 u = __float_as_uint(f);
  u32 r = (u + 0x7FFFu + ((u >> 16) & 1u)) >> 16;   // RNE
  return (u16)r;
}
// NaN-propagating ReLU (fmaxf(NaN,0)=0 would hide poison as zeros)
__device__ __forceinline__ float relu(float x) { return x < 0.f ? 0.f : x; }

// async global->LDS, 16B/lane; LDS dest = wave-uniform base + lane*16
__device__ __forceinline__ void gld16(const void* g, void* l) {
  __builtin_amdgcn_global_load_lds((const __attribute__((address_space(1))) u32*)g,
                                   (__attribute__((address_space(3))) u32*)l, 16, 0, 0);
}

// ---------------------------------------------------------------------------
// 1a. partial column sums of frame batch 0; block (0,0) also zeroes
//     raw1/raw2 (512 floats) — replaces hipMemsetAsync.
__global__ void colmean_part_kernel(const float* __restrict__ frame,
                                    double* __restrict__ partD,
                                    float* __restrict__ rawZ) {
  if (blockIdx.x == 0 && blockIdx.y == 0) {
    rawZ[threadIdx.x] = 0.f;
    rawZ[threadIdx.x + 256] = 0.f;
  }
  int tf = blockIdx.x * 256 + threadIdx.x;           // 4096
  int ch = blockIdx.y;                               // 8 chunks
  const float* f0 = frame + tf + (size_t)ch * 64 * 4096;
  double s = 0.0;
  for (int c = 0; c < 64; ++c) s += (double)f0[(size_t)c * 4096];
  partD[ch * 4096 + tf] = s;
}

// ---------------------------------------------------------------------------
// 2. f64: mean = (in-order chunk combine)/512; S = sum; q = mean/S; cumsum;
//    cdf = min(int(c*2048), 2047).  (Ordering kept exactly as verified —
//    reordering f64 sums risks a 1-ULP cdf flip -> different gather idx.)
__global__ void scanD_kernel(const double* __restrict__ partD, int* __restrict__ cdf) {
  __shared__ double part[256];
  __shared__ double base[256];
  __shared__ double Ss;
  int tid = threadIdx.x;
  double loc[16];
  double s = 0.0;
#pragma unroll
  for (int i = 0; i < 16; ++i) {
    int tf = tid * 16 + i;
    double m = 0.0;
#pragma unroll
    for (int ch = 0; ch < 8; ++ch) m += partD[ch * 4096 + tf];  // in c-order
    loc[i] = m / 512.0;
    s += loc[i];
  }
  part[tid] = s;
  __syncthreads();
  if (tid == 0) {
    double t = 0.0;
    for (int i = 0; i < 256; ++i) t += part[i];
    Ss = t;
  }
  __syncthreads();
  double S = Ss;
  s = 0.0;
#pragma unroll
  for (int i = 0; i < 16; ++i) { loc[i] = loc[i] / S; s += loc[i]; }
  part[tid] = s;
  __syncthreads();
  if (tid == 0) {
    double c = 0.0;
    for (int i = 0; i < 256; ++i) { base[i] = c; c += part[i]; }
  }
  __syncthreads();
  double c = base[tid];
#pragma unroll
  for (int i = 0; i < 16; ++i) {
    c += loc[i];
    int iv = (int)(c * 2048.0);                      // trunc = astype(int32)
    cdf[tid * 16 + i] = iv < 2047 ? iv : 2047;
  }
}

// ---------------------------------------------------------------------------
// first argmin_j |cdf[j]-t| for MONOTONE non-decreasing cdf (r11-verified).
__device__ __forceinline__ int lowbound(const int* __restrict__ cdf, int hi0, int v) {
  int lo = 0, hi = hi0;
  while (lo < hi) { int mid = (lo + hi) >> 1; if (cdf[mid] < v) lo = mid + 1; else hi = mid; }
  return lo;
}
__device__ __forceinline__ int argmin_cdf(const int* __restrict__ cdf, int t) {
  int j2 = lowbound(cdf, 4096, t);       // first index with cdf >= t
  if (j2 == 0) return 0;                 // plateau head of v2 is j2 itself
  if (j2 == 4096) return lowbound(cdf, 4096, cdf[4095]);
  int d2 = cdf[j2] - t, d1 = t - cdf[j2 - 1];
  if (d2 < d1) return j2;                // j2 is first index with value v2
  return lowbound(cdf, j2, cdf[j2 - 1]); // head of v1 plateau (d1<=d2 -> earlier)
}

// ---------------------------------------------------------------------------
// 4+5+6a merged (r10/r11-verified) + inline argmin.
//   z<4: gather X3T; z<8: transpose featT; z>=8: convW12
__global__ void gatherTrans_kernel(const float* __restrict__ frame,
                                   const float* __restrict__ feature,
                                   const int* __restrict__ cdf,
                                   const float* __restrict__ W1,
                                   const float* __restrict__ W2,
                                   u16* __restrict__ X3T, u16* __restrict__ featT,
                                   u16* __restrict__ W12b) {
  __shared__ u16 tile[64][65];
  __shared__ int sidx[64];
  int tid = threadIdx.x;
  int zz = blockIdx.z;
  if (zz >= 8) {                        // weight conversion slice
    int flat = (zz - 8) * 256 + blockIdx.y * 8 + blockIdx.x;   // [0,768)
    int i = (flat * 256 + tid) * 4;
    f32x4 v = *(const f32x4*)(i < 262144 ? W1 + i : W2 + (i - 262144));
    short4_t o;
#pragma unroll
    for (int e = 0; e < 4; ++e) o[e] = (short)f2bf(v[e]);
    *(short4_t*)(W12b + i) = o;
    return;
  }
  int cb = blockIdx.x * 64, t0 = blockIdx.y * 64;
  int b = zz & 3, which = zz >> 2;
  if (which == 0) {
    if (tid < 64) sidx[tid] = argmin_cdf(cdf, t0 + tid);   // in [0,4095]
    __syncthreads();
    const float* fb = frame + (size_t)b * 512 * 4096;
    for (int i = tid; i < 4096; i += 256) {
      int r = i >> 6, tt = i & 63;        // r = c-local, tt = t-local
      tile[tt][r] = f2bf(fb[(size_t)(cb + r) * 4096 + sidx[tt]]);
    }
    __syncthreads();
    u16* xb = X3T + (size_t)b * 2048 * 2048;
    for (int i = tid; i < 4096; i += 256) {
      int r = i >> 6, cc = i & 63;        // r = t-local, cc = c-local
      xb[(size_t)(t0 + r) * 2048 + cb + cc] = tile[r][cc];
    }
  } else {
    const float* xb = feature + (size_t)b * 512 * 2048;
    for (int i = tid; i < 4096; i += 256) {
      int r = i >> 6, tt = i & 63;        // coalesced along t
      tile[tt][r] = f2bf(xb[(size_t)(cb + r) * 2048 + t0 + tt]);
    }
    __syncthreads();
    u16* xtb = featT + (size_t)b * 2048 * 512;
    for (int i = tid; i < 4096; i += 256) {
      int r = i >> 6, cc = i & 63;
      xtb[(size_t)(t0 + r) * 512 + cb + cc] = tile[r][cc];
    }
  }
}

// ---------------------------------------------------------------------------
// 7a. fused GEMM1+2 + GN1/GN2 stats (r2..r14-verified math; r15: SINGLE-buffer
//     LDS). The dbuf prefetch was dead weight: compiler drains vmcnt(0) before
//     every s_barrier (m97), so the prefetch never survives a step boundary —
//     but it cost 2x LDS. Single 12KB buffer -> 12 blocks/CU (VGPR-capped,
//     pinned by __launch_bounds__(128,6)) -> 2x TLP hides the stage latency
//     across blocks (m114 implicit overlap). Swizzle unchanged (conflicts 0).
__global__ __launch_bounds__(128, 6) void gemm12_kernel(
    const u16* __restrict__ A, const u16* __restrict__ Bt,
    const float* __restrict__ b1, const float* __restrict__ b2,
    u16* __restrict__ Y, float* __restrict__ raw1, float* __restrict__ raw2)
{
  const int K = 512;
  __shared__ short As[2048];   // [64 m][32 k]
  __shared__ short Bs[4096];   // [128 n][32 k]
  const int tid = threadIdx.x;
  const int lane = tid & 63;
  const int w = tid >> 6;
  const int nt = blockIdx.x, mt = blockIdx.y, bb = blockIdx.z;
  const u16* Ab = A + (size_t)mt * 64 * K;
  const u16* Bb = Bt + ((size_t)bb * 2048 + (size_t)nt * 128) * K;
  const int lm = lane & 15, lq = lane >> 4;
  f32x4 acc[4][4] = {};

  auto stage = [&](int kt) {
#pragma unroll
    for (int p = 0; p < 2; ++p) {
      int chunk = tid + 128 * p;
      int row = chunk >> 2;
      int ko = ((chunk & 3) ^ ((row >> 1) & 3)) << 3;   // source pre-swizzle
      gld16(Ab + (size_t)row * K + kt + ko, (char*)As + chunk * 16);
    }
#pragma unroll
    for (int p = 0; p < 4; ++p) {
      int chunk = tid + 128 * p;
      int row = chunk >> 2;
      int ko = ((chunk & 3) ^ ((row >> 1) & 3)) << 3;
      gld16(Bb + (size_t)row * K + kt + ko, (char*)Bs + chunk * 16);
    }
  };

  for (int s = 0; s < 16; ++s) {
    if (s) __syncthreads();             // prev compute done reading LDS
    stage(s << 5);
    __syncthreads();                    // staged (vmcnt(0) drained by barrier)
    short8 af[4], bfv[4];
#pragma unroll
    for (int i = 0; i < 4; ++i) {
      int r = i * 16 + lm;
      af[i] = *(const short8*)(As + r * 32 + ((lq ^ ((r >> 1) & 3)) << 3));
    }
#pragma unroll
    for (int j = 0; j < 4; ++j) {
      int r = w * 64 + j * 16 + lm;
      bfv[j] = *(const short8*)(Bs + r * 32 + ((lq ^ ((r >> 1) & 3)) << 3));
    }
#pragma unroll
    for (int i = 0; i < 4; ++i)
#pragma unroll
      for (int j = 0; j < 4; ++j)
        acc[i][j] = __builtin_amdgcn_mfma_f32_16x16x32_bf16(af[i], bfv[j], acc[i][j], 0, 0, 0);
  }

  float s1[4] = {0.f, 0.f, 0.f, 0.f};
  float s2[4] = {0.f, 0.f, 0.f, 0.f};
#pragma unroll
  for (int i = 0; i < 4; ++i) {
    int mbase = mt * 64 + i * 16 + lq * 4;
#pragma unroll
    for (int e = 0; e < 4; ++e) {
      int m = mbase + e;
      float bv = m < 512 ? b1[m] : b2[m - 512];
      u16* yp = Y + ((size_t)bb * 1536 + m) * 2048 + nt * 128 + w * 64 + lm;
#pragma unroll
      for (int j = 0; j < 4; ++j) {
        float v = acc[i][j][e] + bv;
        yp[j * 16] = f2bf(v);
        s1[i] += v; s2[i] += v * v;
      }
    }
  }
#pragma unroll
  for (int i = 0; i < 4; ++i) {
#pragma unroll
    for (int off = 32; off > 0; off >>= 1) {
      s1[i] += __shfl_xor(s1[i], off);
      s2[i] += __shfl_xor(s2[i], off);
    }
  }
  if (lane == 0) {
    if (mt < 8) {                                  // GN1: cpg=16, frag = 1 group
#pragma unroll
      for (int i = 0; i < 4; ++i) {
        int g = mt * 4 + i;
        atomicAdd(&raw1[(bb * 32 + g) * 2],     s1[i]);
        atomicAdd(&raw1[(bb * 32 + g) * 2 + 1], s2[i]);
      }
    } else {                                       // GN2: cpg=32, 2 frags = 1 group
#pragma unroll
      for (int i = 0; i < 2; ++i) {
        int g = (mt - 8) * 2 + i;
        atomicAdd(&raw2[(bb * 32 + g) * 2],     s1[2 * i] + s1[2 * i + 1]);
        atomicAdd(&raw2[(bb * 32 + g) * 2 + 1], s2[2 * i] + s2[2 * i + 1]);
      }
    }
  }
}

// ---------------------------------------------------------------------------
// 7b. GEMM3 split-K x2 (r2..r14-verified math; r15: SINGLE-buffer LDS, same
//     rationale as gemm12 — 12 blocks/CU vs 6). bf16 partials (r14-verified).
__global__ __launch_bounds__(128, 6) void gemm3s_kernel(
    const u16* __restrict__ A, const u16* __restrict__ Bt,
    const float* __restrict__ bias, u16* __restrict__ Yp)
{
  const int K = 2048;
  __shared__ short As[2048];
  __shared__ short Bs[4096];
  const int tid = threadIdx.x;
  const int lane = tid & 63;
  const int w = tid >> 6;
  const int nt = blockIdx.x, mt = blockIdx.y;
  const int bb = blockIdx.z >> 1, ks = blockIdx.z & 1;
  const u16* Ab = A + (size_t)mt * 64 * K + ks * 1024;
  const u16* Bb = Bt + ((size_t)bb * 2048 + (size_t)nt * 128) * K + ks * 1024;
  const int lm = lane & 15, lq = lane >> 4;
  f32x4 acc[4][4] = {};

  auto stage = [&](int kt) {
#pragma unroll
    for (int p = 0; p < 2; ++p) {
      int chunk = tid + 128 * p;
      int row = chunk >> 2;
      int ko = ((chunk & 3) ^ ((row >> 1) & 3)) << 3;
      gld16(Ab + (size_t)row * K + kt + ko, (char*)As + chunk * 16);
    }
#pragma unroll
    for (int p = 0; p < 4; ++p) {
      int chunk = tid + 128 * p;
      int row = chunk >> 2;
      int ko = ((chunk & 3) ^ ((row >> 1) & 3)) << 3;
      gld16(Bb + (size_t)row * K + kt + ko, (char*)Bs + chunk * 16);
    }
  };

  for (int s = 0; s < 32; ++s) {
    if (s) __syncthreads();
    stage(s << 5);
    __syncthreads();
    short8 af[4], bfv[4];
#pragma unroll
    for (int i = 0; i < 4; ++i) {
      int r = i * 16 + lm;
      af[i] = *(const short8*)(As + r * 32 + ((lq ^ ((r >> 1) & 3)) << 3));
    }
#pragma unroll
    for (int j = 0; j < 4; ++j) {
      int r = w * 64 + j * 16 + lm;
      bfv[j] = *(const short8*)(Bs + r * 32 + ((lq ^ ((r >> 1) & 3)) << 3));
    }
#pragma unroll
    for (int i = 0; i < 4; ++i)
#pragma unroll
      for (int j = 0; j < 4; ++j)
        acc[i][j] = __builtin_amdgcn_mfma_f32_16x16x32_bf16(af[i], bfv[j], acc[i][j], 0, 0, 0);
  }
#pragma unroll
  for (int i = 0; i < 4; ++i) {
    int mbase = mt * 64 + i * 16 + lq * 4;
#pragma unroll
    for (int e = 0; e < 4; ++e) {
      int m = mbase + e;
      float bv = ks ? 0.f : bias[m];
      u16* yp = Yp + ((size_t)(ks * 4 + bb) * 512 + m) * 2048 + nt * 128 + w * 64 + lm;
#pragma unroll
      for (int j = 0; j < 4; ++j)
        yp[j * 16] = f2bf(acc[i][j][e] + bv);
    }
  }
}

// ---------------------------------------------------------------------------
// 9. normT1+normT2 merged (r8-verified) + convW(W3) folded as y==24 slice.
//    Reads BF16 Y12 (r14-verified).
__global__ void normT12_kernel(const u16* __restrict__ Y,
                               const float* __restrict__ raw1,
                               const float* __restrict__ raw2,
                               const float* __restrict__ g1, const float* __restrict__ be1,
                               const float* __restrict__ g2, const float* __restrict__ be2,
                               const float* __restrict__ W3, u16* __restrict__ W3b,
                               u16* __restrict__ X3T, float* __restrict__ featOut) {
  __shared__ u16 tile[64][65];           // [t_local][c_local]
  int b = blockIdx.z, t0 = blockIdx.x * 64;
  int yb_idx = blockIdx.y;
  if (yb_idx == 24) {                    // W3 -> bf16 slice: 128 blocks
    int flat = blockIdx.z * 32 + blockIdx.x;            // [0,128)
#pragma unroll
    for (int k = 0; k < 8; ++k) {
      int i = (flat * 2048 + k * 256 + threadIdx.x) * 4;  // 1048576 u16 total
      f32x4 v = *(const f32x4*)(W3 + i);
      short4_t o;
#pragma unroll
      for (int e = 0; e < 4; ++e) o[e] = (short)f2bf(v[e]);
      *(short4_t*)(W3b + i) = o;
    }
    return;
  }
  const int gn2 = yb_idx >= 8;
  int c0 = (gn2 ? yb_idx - 8 : yb_idx) * 64;
  const float* raw   = gn2 ? raw2 : raw1;
  const float* gamma = gn2 ? g2 : g1;
  const float* beta  = gn2 ? be2 : be1;
  const float inv_n  = gn2 ? (1.f / 65536.f) : (1.f / 32768.f);
  const int chBase   = gn2 ? 512 : 0;
  const int gShift   = gn2 ? 5 : 4;
  const int colBase  = gn2 ? 512 : 1536;
  const u16* yb = Y + ((size_t)b * 1536 + chBase) * 2048;
  for (int i = threadIdx.x; i < 4096; i += 256) {
    int r = i >> 6, cc = i & 63;         // r: channel-local, cc: t-local
    int ch = c0 + r;
    int gI = (b * 32 + (ch >> gShift)) * 2;
    float mu = raw[gI] * inv_n;
    float var = raw[gI + 1] * inv_n - mu * mu;
    float rs = 1.0f / sqrtf(var + 1e-5f);
    float v = bf2f(yb[(size_t)ch * 2048 + t0 + cc]);
    float o = relu((v - mu) * rs * gamma[ch] + beta[ch]);
    tile[cc][r] = f2bf(o);
    if (gn2) featOut[((size_t)b * 1024 + ch) * 2048 + t0 + cc] = o;
  }
  __syncthreads();
  for (int i = threadIdx.x; i < 4096; i += 256) {
    int r = i >> 6, cc = i & 63;         // r: t-local, cc: c-local
    X3T[((size_t)b * 2048 + t0 + r) * 2048 + colBase + c0 + cc] = tile[r][cc];
  }
}

// ---------------------------------------------------------------------------
// 10. MERGED stats+GN+ReLU for split-K Y3 (r12/r14-verified). BF16 partials
//     read once into registers; intra-block reduce; write fp32 out.
__global__ __launch_bounds__(1024) void norm3g_kernel(
    const u16* __restrict__ Yp,
    const float* __restrict__ gamma, const float* __restrict__ beta,
    float* __restrict__ out)
{
  const int tid = threadIdx.x;          // 1024
  const int g = blockIdx.x;             // 32 groups
  const int b = blockIdx.y;             // 4 batches
  const short8* a8 = (const short8*)(Yp + ((size_t)b * 512 + g * 16) * 2048);
  const short8* c8 = a8 + 524288;       // ks=1 partial at +4*512*2048 u16
  float v[4][8];
  float s = 0.f, ss = 0.f;
#pragma unroll
  for (int k = 0; k < 4; ++k) {
    int f = tid + k * 1024;             // [0,4096) short8 within group
    short8 a = a8[f], c = c8[f];
#pragma unroll
    for (int e = 0; e < 8; ++e) {
      float x = bf2f((u16)a[e]) + bf2f((u16)c[e]);
      v[k][e] = x;
      s += x; ss += x * x;
    }
  }
#pragma unroll
  for (int off = 32; off > 0; off >>= 1) {
    s  += __shfl_xor(s, off);
    ss += __shfl_xor(ss, off);
  }
  __shared__ float w1[16], w2[16];
  __shared__ float stat[2];
  int wave = tid >> 6, lane = tid & 63;
  if (lane == 0) { w1[wave] = s; w2[wave] = ss; }
  __syncthreads();
  if (tid == 0) {
    float t1 = 0.f, t2 = 0.f;
    for (int i = 0; i < 16; ++i) { t1 += w1[i]; t2 += w2[i]; }
    float mu = t1 * (1.f / 32768.f);
    stat[0] = mu;
    stat[1] = 1.0f / sqrtf(t2 * (1.f / 32768.f) - mu * mu + 1e-5f);
  }
  __syncthreads();
  const float mu = stat[0], rs = stat[1];
  f32x4* orow = (f32x4*)(out + ((size_t)b * 512 + g * 16) * 2048);
#pragma unroll
  for (int k = 0; k < 4; ++k) {
    int f = tid + k * 1024;
    int ch = g * 16 + (f >> 8);         // 256 short8 per channel row
    float ga = gamma[ch], bt = beta[ch];
    f32x4 o0, o1;
#pragma unroll
    for (int e = 0; e < 4; ++e) {
      o0[e] = relu((v[k][e]     - mu) * rs * ga + bt);
      o1[e] = relu((v[k][4 + e] - mu) * rs * ga + bt);
    }
    orow[f * 2]     = o0;
    orow[f * 2 + 1] = o1;
  }
}

// ---------------------------------------------------------------------------
extern "C" void kernel_launch(void* const* d_in, const int* in_sizes, int n_in,
                              void* d_out, int out_size, void* d_ws, size_t ws_size,
                              hipStream_t stream) {
  const float* feature = (const float*)d_in[0];
  const float* frame   = (const float*)d_in[1];
  const float* W1 = (const float*)d_in[2];
  const float* b1 = (const float*)d_in[3];
  const float* g1 = (const float*)d_in[4];
  const float* be1 = (const float*)d_in[5];
  const float* W2 = (const float*)d_in[6];
  const float* b2 = (const float*)d_in[7];
  const float* g2 = (const float*)d_in[8];
  const float* be2 = (const float*)d_in[9];
  const float* W3 = (const float*)d_in[10];
  const float* b3 = (const float*)d_in[11];
  const float* g3 = (const float*)d_in[12];
  const float* be3 = (const float*)d_in[13];

  char* ws = (char*)d_ws;
  // Layout / stream-ordered aliasing (r13/r14-verified):
  //   X3T   [0, 32MiB)            bf16 (B,2048t,2048c)
  //   Y12b  [32MiB, 56MiB)        bf16 (B,1536,2048) = GEMM1+2 output
  //   Y3p   [32MiB, 48MiB)        bf16 split-K partial pair (after normT12;
  //                               aliases dead Y12b — stream-ordered)
  //   partD [48MiB, +256KiB)      f64, dead before gemm12 writes Y12b
  //   featT [80MiB, 88MiB)        bf16 (B,2048,512); W3b aliases it after
  //                               gemm12 (featT dead; normT12 writes W3b)
  //   W12b  [88MiB, +1.5MiB)      bf16 stacked W1;W2
  //   small tail after W12b (cdf/raw1/raw2)
  u16*    X3T   = (u16*)(ws + 0);
  u16*    Y12b  = (u16*)(ws + 33554432);
  u16*    Y3p   = (u16*)(ws + 33554432);   // aliases dead Y12b
  double* partD = (double*)(ws + 50331648);
  u16*    featT = (u16*)(ws + 83886080);
  u16*    W3b   = (u16*)(ws + 83886080);   // aliases dead featT
  u16*    W12b  = (u16*)(ws + 92274688);
  int*    cdf   = (int*)(ws + 93847552);
  float*  raw1  = (float*)(ws + 93872128);
  float*  raw2  = (float*)(ws + 93873152);

  float* outMixed = (float*)d_out;                       // (B,512,2048) fp32
  float* outFeat  = outMixed + (size_t)4 * 512 * 2048;   // (B,1024,2048) fp32

  colmean_part_kernel<<<dim3(16, 8), 256, 0, stream>>>(frame, partD, raw1);
  scanD_kernel<<<1, 256, 0, stream>>>(partD, cdf);
  gatherTrans_kernel<<<dim3(8, 32, 11), 256, 0, stream>>>(frame, feature, cdf,
                                                          W1, W2, X3T, featT, W12b);
  gemm12_kernel<<<dim3(16, 24, 4), 128, 0, stream>>>(W12b, featT, b1, b2, Y12b,
                                                     raw1, raw2);
  normT12_kernel<<<dim3(32, 25, 4), 256, 0, stream>>>(Y12b, raw1, raw2,
                                                      g1, be1, g2, be2,
                                                      W3, W3b, X3T, outFeat);
  gemm3s_kernel<<<dim3(16, 8, 8), 128, 0, stream>>>(W3b, X3T, b3, Y3p);
  norm3g_kernel<<<dim3(32, 4), 1024, 0, stream>>>(Y3p, g3, be3, outMixed);
}

// Round 16
// 257.130 us; speedup vs baseline: 1.5948x; 1.5948x over previous
//
#include <hip/hip_runtime.h>

typedef unsigned short u16;
typedef unsigned int   u32;
typedef __attribute__((ext_vector_type(8))) short short8;
typedef __attribute__((ext_vector_type(4))) short short4_t;
typedef __attribute__((ext_vector_type(4))) float f32x4;

__device__ __forceinline__ float bf2f(u16 v) {
  return __uint_as_float(((u32)v) << 16);
}
__device__ __forceinline__ u16 f2bf(float f) {
  u32 u = __float_as_uint(f);
  u32 r = (u + 0x7FFFu + ((u >> 16) & 1u)) >> 16;   // RNE
  return (u16)r;
}
// NaN-propagating ReLU (fmaxf(NaN,0)=0 would hide poison as zeros)
__device__ __forceinline__ float relu(float x) { return x < 0.f ? 0.f : x; }

// async global->LDS, 16B/lane; LDS dest = wave-uniform base + lane*16
__device__ __forceinline__ void gld16(const void* g, void* l) {
  __builtin_amdgcn_global_load_lds((const __attribute__((address_space(1))) u32*)g,
                                   (__attribute__((address_space(3))) u32*)l, 16, 0, 0);
}

// ---------------------------------------------------------------------------
// 1a. partial column sums of frame batch 0; block (0,0) also zeroes
//     raw1/raw2 (512 floats) — replaces hipMemsetAsync.
__global__ void colmean_part_kernel(const float* __restrict__ frame,
                                    double* __restrict__ partD,
                                    float* __restrict__ rawZ) {
  if (blockIdx.x == 0 && blockIdx.y == 0) {
    rawZ[threadIdx.x] = 0.f;
    rawZ[threadIdx.x + 256] = 0.f;
  }
  int tf = blockIdx.x * 256 + threadIdx.x;           // 4096
  int ch = blockIdx.y;                               // 8 chunks
  const float* f0 = frame + tf + (size_t)ch * 64 * 4096;
  double s = 0.0;
  for (int c = 0; c < 64; ++c) s += (double)f0[(size_t)c * 4096];
  partD[ch * 4096 + tf] = s;
}

// ---------------------------------------------------------------------------
// 2. f64: mean = (in-order chunk combine)/512; S = sum; q = mean/S; cumsum;
//    cdf = min(int(c*2048), 2047).  (Ordering kept exactly as verified —
//    reordering f64 sums risks a 1-ULP cdf flip -> different gather idx.)
__global__ void scanD_kernel(const double* __restrict__ partD, int* __restrict__ cdf) {
  __shared__ double part[256];
  __shared__ double base[256];
  __shared__ double Ss;
  int tid = threadIdx.x;
  double loc[16];
  double s = 0.0;
#pragma unroll
  for (int i = 0; i < 16; ++i) {
    int tf = tid * 16 + i;
    double m = 0.0;
#pragma unroll
    for (int ch = 0; ch < 8; ++ch) m += partD[ch * 4096 + tf];  // in c-order
    loc[i] = m / 512.0;
    s += loc[i];
  }
  part[tid] = s;
  __syncthreads();
  if (tid == 0) {
    double t = 0.0;
    for (int i = 0; i < 256; ++i) t += part[i];
    Ss = t;
  }
  __syncthreads();
  double S = Ss;
  s = 0.0;
#pragma unroll
  for (int i = 0; i < 16; ++i) { loc[i] = loc[i] / S; s += loc[i]; }
  part[tid] = s;
  __syncthreads();
  if (tid == 0) {
    double c = 0.0;
    for (int i = 0; i < 256; ++i) { base[i] = c; c += part[i]; }
  }
  __syncthreads();
  double c = base[tid];
#pragma unroll
  for (int i = 0; i < 16; ++i) {
    c += loc[i];
    int iv = (int)(c * 2048.0);                      // trunc = astype(int32)
    cdf[tid * 16 + i] = iv < 2047 ? iv : 2047;
  }
}

// ---------------------------------------------------------------------------
// first argmin_j |cdf[j]-t| for MONOTONE non-decreasing cdf (r11-verified).
__device__ __forceinline__ int lowbound(const int* __restrict__ cdf, int hi0, int v) {
  int lo = 0, hi = hi0;
  while (lo < hi) { int mid = (lo + hi) >> 1; if (cdf[mid] < v) lo = mid + 1; else hi = mid; }
  return lo;
}
__device__ __forceinline__ int argmin_cdf(const int* __restrict__ cdf, int t) {
  int j2 = lowbound(cdf, 4096, t);       // first index with cdf >= t
  if (j2 == 0) return 0;                 // plateau head of v2 is j2 itself
  if (j2 == 4096) return lowbound(cdf, 4096, cdf[4095]);
  int d2 = cdf[j2] - t, d1 = t - cdf[j2 - 1];
  if (d2 < d1) return j2;                // j2 is first index with value v2
  return lowbound(cdf, j2, cdf[j2 - 1]); // head of v1 plateau (d1<=d2 -> earlier)
}

// ---------------------------------------------------------------------------
// 4+5+6a merged (r10/r11-verified) + inline argmin.
//   z<4: gather X3T; z<8: transpose featT; z>=8: convW12
__global__ void gatherTrans_kernel(const float* __restrict__ frame,
                                   const float* __restrict__ feature,
                                   const int* __restrict__ cdf,
                                   const float* __restrict__ W1,
                                   const float* __restrict__ W2,
                                   u16* __restrict__ X3T, u16* __restrict__ featT,
                                   u16* __restrict__ W12b) {
  __shared__ u16 tile[64][65];
  __shared__ int sidx[64];
  int tid = threadIdx.x;
  int zz = blockIdx.z;
  if (zz >= 8) {                        // weight conversion slice
    int flat = (zz - 8) * 256 + blockIdx.y * 8 + blockIdx.x;   // [0,768)
    int i = (flat * 256 + tid) * 4;
    f32x4 v = *(const f32x4*)(i < 262144 ? W1 + i : W2 + (i - 262144));
    short4_t o;
#pragma unroll
    for (int e = 0; e < 4; ++e) o[e] = (short)f2bf(v[e]);
    *(short4_t*)(W12b + i) = o;
    return;
  }
  int cb = blockIdx.x * 64, t0 = blockIdx.y * 64;
  int b = zz & 3, which = zz >> 2;
  if (which == 0) {
    if (tid < 64) sidx[tid] = argmin_cdf(cdf, t0 + tid);   // in [0,4095]
    __syncthreads();
    const float* fb = frame + (size_t)b * 512 * 4096;
    for (int i = tid; i < 4096; i += 256) {
      int r = i >> 6, tt = i & 63;        // r = c-local, tt = t-local
      tile[tt][r] = f2bf(fb[(size_t)(cb + r) * 4096 + sidx[tt]]);
    }
    __syncthreads();
    u16* xb = X3T + (size_t)b * 2048 * 2048;
    for (int i = tid; i < 4096; i += 256) {
      int r = i >> 6, cc = i & 63;        // r = t-local, cc = c-local
      xb[(size_t)(t0 + r) * 2048 + cb + cc] = tile[r][cc];
    }
  } else {
    const float* xb = feature + (size_t)b * 512 * 2048;
    for (int i = tid; i < 4096; i += 256) {
      int r = i >> 6, tt = i & 63;        // coalesced along t
      tile[tt][r] = f2bf(xb[(size_t)(cb + r) * 2048 + t0 + tt]);
    }
    __syncthreads();
    u16* xtb = featT + (size_t)b * 2048 * 512;
    for (int i = tid; i < 4096; i += 256) {
      int r = i >> 6, cc = i & 63;
      xtb[(size_t)(t0 + r) * 512 + cb + cc] = tile[r][cc];
    }
  }
}

// ---------------------------------------------------------------------------
// 7a. fused GEMM1+2 (r14-verified, EXACT revert): Y12 bf16 + bias; GN1/GN2
//     stats fused. M=1536, N=2048, K=512. 64x128 tile, 2 waves, dbuf.
//     Conflict-free both-sides 16B-slot XOR swizzle. 1536 blocks = 6/CU
//     (grid-limited — r15 post-mortem: LDS capacity was never the limiter;
//     forcing 6 waves/SIMD spilled acc to scratch, 317MB writes, 2.8x slower).
__global__ __launch_bounds__(128) void gemm12_kernel(
    const u16* __restrict__ A, const u16* __restrict__ Bt,
    const float* __restrict__ b1, const float* __restrict__ b2,
    u16* __restrict__ Y, float* __restrict__ raw1, float* __restrict__ raw2)
{
  const int K = 512;
  __shared__ short As[2][2048];   // [buf][64 m][32 k]
  __shared__ short Bs[2][4096];   // [buf][128 n][32 k]
  const int tid = threadIdx.x;
  const int lane = tid & 63;
  const int w = tid >> 6;
  const int nt = blockIdx.x, mt = blockIdx.y, bb = blockIdx.z;
  const u16* Ab = A + (size_t)mt * 64 * K;
  const u16* Bb = Bt + ((size_t)bb * 2048 + (size_t)nt * 128) * K;
  const int lm = lane & 15, lq = lane >> 4;
  f32x4 acc[4][4] = {};

  auto stage = [&](int buf, int kt) {
#pragma unroll
    for (int p = 0; p < 2; ++p) {
      int chunk = tid + 128 * p;
      int row = chunk >> 2;
      int ko = ((chunk & 3) ^ ((row >> 1) & 3)) << 3;   // source pre-swizzle
      gld16(Ab + (size_t)row * K + kt + ko, (char*)As[buf] + chunk * 16);
    }
#pragma unroll
    for (int p = 0; p < 4; ++p) {
      int chunk = tid + 128 * p;
      int row = chunk >> 2;
      int ko = ((chunk & 3) ^ ((row >> 1) & 3)) << 3;
      gld16(Bb + (size_t)row * K + kt + ko, (char*)Bs[buf] + chunk * 16);
    }
  };

  stage(0, 0);
  for (int s = 0; s < 16; ++s) {
    int cur = s & 1;
    __syncthreads();
    if (s + 1 < 16) stage(cur ^ 1, (s + 1) << 5);
    short8 af[4], bfv[4];
#pragma unroll
    for (int i = 0; i < 4; ++i) {
      int r = i * 16 + lm;
      af[i] = *(const short8*)(As[cur] + r * 32 + ((lq ^ ((r >> 1) & 3)) << 3));
    }
#pragma unroll
    for (int j = 0; j < 4; ++j) {
      int r = w * 64 + j * 16 + lm;
      bfv[j] = *(const short8*)(Bs[cur] + r * 32 + ((lq ^ ((r >> 1) & 3)) << 3));
    }
#pragma unroll
    for (int i = 0; i < 4; ++i)
#pragma unroll
      for (int j = 0; j < 4; ++j)
        acc[i][j] = __builtin_amdgcn_mfma_f32_16x16x32_bf16(af[i], bfv[j], acc[i][j], 0, 0, 0);
  }

  float s1[4] = {0.f, 0.f, 0.f, 0.f};
  float s2[4] = {0.f, 0.f, 0.f, 0.f};
#pragma unroll
  for (int i = 0; i < 4; ++i) {
    int mbase = mt * 64 + i * 16 + lq * 4;
#pragma unroll
    for (int e = 0; e < 4; ++e) {
      int m = mbase + e;
      float bv = m < 512 ? b1[m] : b2[m - 512];
      u16* yp = Y + ((size_t)bb * 1536 + m) * 2048 + nt * 128 + w * 64 + lm;
#pragma unroll
      for (int j = 0; j < 4; ++j) {
        float v = acc[i][j][e] + bv;
        yp[j * 16] = f2bf(v);
        s1[i] += v; s2[i] += v * v;
      }
    }
  }
#pragma unroll
  for (int i = 0; i < 4; ++i) {
#pragma unroll
    for (int off = 32; off > 0; off >>= 1) {
      s1[i] += __shfl_xor(s1[i], off);
      s2[i] += __shfl_xor(s2[i], off);
    }
  }
  if (lane == 0) {
    if (mt < 8) {                                  // GN1: cpg=16, frag = 1 group
#pragma unroll
      for (int i = 0; i < 4; ++i) {
        int g = mt * 4 + i;
        atomicAdd(&raw1[(bb * 32 + g) * 2],     s1[i]);
        atomicAdd(&raw1[(bb * 32 + g) * 2 + 1], s2[i]);
      }
    } else {                                       // GN2: cpg=32, 2 frags = 1 group
#pragma unroll
      for (int i = 0; i < 2; ++i) {
        int g = (mt - 8) * 2 + i;
        atomicAdd(&raw2[(bb * 32 + g) * 2],     s1[2 * i] + s1[2 * i + 1]);
        atomicAdd(&raw2[(bb * 32 + g) * 2 + 1], s2[2 * i] + s2[2 * i + 1]);
      }
    }
  }
}

// ---------------------------------------------------------------------------
// 7b. GEMM3 split-K x2 (r14-verified, EXACT revert). M=512, N=2048, K=2048.
//     64x128 tile, 2 waves, dbuf, grid.z = b*2+ks -> 1024 blocks. bf16
//     partials. Fusion/occupancy post-mortems r5/r6/r9/r10/r15: chain stays.
__global__ __launch_bounds__(128) void gemm3s_kernel(
    const u16* __restrict__ A, const u16* __restrict__ Bt,
    const float* __restrict__ bias, u16* __restrict__ Yp)
{
  const int K = 2048;
  __shared__ short As[2][2048];
  __shared__ short Bs[2][4096];
  const int tid = threadIdx.x;
  const int lane = tid & 63;
  const int w = tid >> 6;
  const int nt = blockIdx.x, mt = blockIdx.y;
  const int bb = blockIdx.z >> 1, ks = blockIdx.z & 1;
  const u16* Ab = A + (size_t)mt * 64 * K + ks * 1024;
  const u16* Bb = Bt + ((size_t)bb * 2048 + (size_t)nt * 128) * K + ks * 1024;
  const int lm = lane & 15, lq = lane >> 4;
  f32x4 acc[4][4] = {};

  auto stage = [&](int buf, int kt) {
#pragma unroll
    for (int p = 0; p < 2; ++p) {
      int chunk = tid + 128 * p;
      int row = chunk >> 2;
      int ko = ((chunk & 3) ^ ((row >> 1) & 3)) << 3;
      gld16(Ab + (size_t)row * K + kt + ko, (char*)As[buf] + chunk * 16);
    }
#pragma unroll
    for (int p = 0; p < 4; ++p) {
      int chunk = tid + 128 * p;
      int row = chunk >> 2;
      int ko = ((chunk & 3) ^ ((row >> 1) & 3)) << 3;
      gld16(Bb + (size_t)row * K + kt + ko, (char*)Bs[buf] + chunk * 16);
    }
  };

  stage(0, 0);
  for (int s = 0; s < 32; ++s) {
    int cur = s & 1;
    __syncthreads();
    if (s + 1 < 32) stage(cur ^ 1, (s + 1) << 5);
    short8 af[4], bfv[4];
#pragma unroll
    for (int i = 0; i < 4; ++i) {
      int r = i * 16 + lm;
      af[i] = *(const short8*)(As[cur] + r * 32 + ((lq ^ ((r >> 1) & 3)) << 3));
    }
#pragma unroll
    for (int j = 0; j < 4; ++j) {
      int r = w * 64 + j * 16 + lm;
      bfv[j] = *(const short8*)(Bs[cur] + r * 32 + ((lq ^ ((r >> 1) & 3)) << 3));
    }
#pragma unroll
    for (int i = 0; i < 4; ++i)
#pragma unroll
      for (int j = 0; j < 4; ++j)
        acc[i][j] = __builtin_amdgcn_mfma_f32_16x16x32_bf16(af[i], bfv[j], acc[i][j], 0, 0, 0);
  }
#pragma unroll
  for (int i = 0; i < 4; ++i) {
    int mbase = mt * 64 + i * 16 + lq * 4;
#pragma unroll
    for (int e = 0; e < 4; ++e) {
      int m = mbase + e;
      float bv = ks ? 0.f : bias[m];
      u16* yp = Yp + ((size_t)(ks * 4 + bb) * 512 + m) * 2048 + nt * 128 + w * 64 + lm;
#pragma unroll
      for (int j = 0; j < 4; ++j)
        yp[j * 16] = f2bf(acc[i][j][e] + bv);
    }
  }
}

// ---------------------------------------------------------------------------
// 9. normT1+normT2 merged (r8-verified) + convW(W3) folded as y==24 slice.
//    Reads BF16 Y12 (r14-verified).
__global__ void normT12_kernel(const u16* __restrict__ Y,
                               const float* __restrict__ raw1,
                               const float* __restrict__ raw2,
                               const float* __restrict__ g1, const float* __restrict__ be1,
                               const float* __restrict__ g2, const float* __restrict__ be2,
                               const float* __restrict__ W3, u16* __restrict__ W3b,
                               u16* __restrict__ X3T, float* __restrict__ featOut) {
  __shared__ u16 tile[64][65];           // [t_local][c_local]
  int b = blockIdx.z, t0 = blockIdx.x * 64;
  int yb_idx = blockIdx.y;
  if (yb_idx == 24) {                    // W3 -> bf16 slice: 128 blocks
    int flat = blockIdx.z * 32 + blockIdx.x;            // [0,128)
#pragma unroll
    for (int k = 0; k < 8; ++k) {
      int i = (flat * 2048 + k * 256 + threadIdx.x) * 4;  // 1048576 u16 total
      f32x4 v = *(const f32x4*)(W3 + i);
      short4_t o;
#pragma unroll
      for (int e = 0; e < 4; ++e) o[e] = (short)f2bf(v[e]);
      *(short4_t*)(W3b + i) = o;
    }
    return;
  }
  const int gn2 = yb_idx >= 8;
  int c0 = (gn2 ? yb_idx - 8 : yb_idx) * 64;
  const float* raw   = gn2 ? raw2 : raw1;
  const float* gamma = gn2 ? g2 : g1;
  const float* beta  = gn2 ? be2 : be1;
  const float inv_n  = gn2 ? (1.f / 65536.f) : (1.f / 32768.f);
  const int chBase   = gn2 ? 512 : 0;
  const int gShift   = gn2 ? 5 : 4;
  const int colBase  = gn2 ? 512 : 1536;
  const u16* yb = Y + ((size_t)b * 1536 + chBase) * 2048;
  for (int i = threadIdx.x; i < 4096; i += 256) {
    int r = i >> 6, cc = i & 63;         // r: channel-local, cc: t-local
    int ch = c0 + r;
    int gI = (b * 32 + (ch >> gShift)) * 2;
    float mu = raw[gI] * inv_n;
    float var = raw[gI + 1] * inv_n - mu * mu;
    float rs = 1.0f / sqrtf(var + 1e-5f);
    float v = bf2f(yb[(size_t)ch * 2048 + t0 + cc]);
    float o = relu((v - mu) * rs * gamma[ch] + beta[ch]);
    tile[cc][r] = f2bf(o);
    if (gn2) featOut[((size_t)b * 1024 + ch) * 2048 + t0 + cc] = o;
  }
  __syncthreads();
  for (int i = threadIdx.x; i < 4096; i += 256) {
    int r = i >> 6, cc = i & 63;         // r: t-local, cc: c-local
    X3T[((size_t)b * 2048 + t0 + r) * 2048 + colBase + c0 + cc] = tile[r][cc];
  }
}

// ---------------------------------------------------------------------------
// 10. MERGED stats+GN+ReLU for split-K Y3 (r12/r14-verified). BF16 partials
//     read once into registers; intra-block reduce; write fp32 out.
__global__ __launch_bounds__(1024) void norm3g_kernel(
    const u16* __restrict__ Yp,
    const float* __restrict__ gamma, const float* __restrict__ beta,
    float* __restrict__ out)
{
  const int tid = threadIdx.x;          // 1024
  const int g = blockIdx.x;             // 32 groups
  const int b = blockIdx.y;             // 4 batches
  const short8* a8 = (const short8*)(Yp + ((size_t)b * 512 + g * 16) * 2048);
  const short8* c8 = a8 + 524288;       // ks=1 partial at +4*512*2048 u16
  float v[4][8];
  float s = 0.f, ss = 0.f;
#pragma unroll
  for (int k = 0; k < 4; ++k) {
    int f = tid + k * 1024;             // [0,4096) short8 within group
    short8 a = a8[f], c = c8[f];
#pragma unroll
    for (int e = 0; e < 8; ++e) {
      float x = bf2f((u16)a[e]) + bf2f((u16)c[e]);
      v[k][e] = x;
      s += x; ss += x * x;
    }
  }
#pragma unroll
  for (int off = 32; off > 0; off >>= 1) {
    s  += __shfl_xor(s, off);
    ss += __shfl_xor(ss, off);
  }
  __shared__ float w1[16], w2[16];
  __shared__ float stat[2];
  int wave = tid >> 6, lane = tid & 63;
  if (lane == 0) { w1[wave] = s; w2[wave] = ss; }
  __syncthreads();
  if (tid == 0) {
    float t1 = 0.f, t2 = 0.f;
    for (int i = 0; i < 16; ++i) { t1 += w1[i]; t2 += w2[i]; }
    float mu = t1 * (1.f / 32768.f);
    stat[0] = mu;
    stat[1] = 1.0f / sqrtf(t2 * (1.f / 32768.f) - mu * mu + 1e-5f);
  }
  __syncthreads();
  const float mu = stat[0], rs = stat[1];
  f32x4* orow = (f32x4*)(out + ((size_t)b * 512 + g * 16) * 2048);
#pragma unroll
  for (int k = 0; k < 4; ++k) {
    int f = tid + k * 1024;
    int ch = g * 16 + (f >> 8);         // 256 short8 per channel row
    float ga = gamma[ch], bt = beta[ch];
    f32x4 o0, o1;
#pragma unroll
    for (int e = 0; e < 4; ++e) {
      o0[e] = relu((v[k][e]     - mu) * rs * ga + bt);
      o1[e] = relu((v[k][4 + e] - mu) * rs * ga + bt);
    }
    orow[f * 2]     = o0;
    orow[f * 2 + 1] = o1;
  }
}

// ---------------------------------------------------------------------------
extern "C" void kernel_launch(void* const* d_in, const int* in_sizes, int n_in,
                              void* d_out, int out_size, void* d_ws, size_t ws_size,
                              hipStream_t stream) {
  const float* feature = (const float*)d_in[0];
  const float* frame   = (const float*)d_in[1];
  const float* W1 = (const float*)d_in[2];
  const float* b1 = (const float*)d_in[3];
  const float* g1 = (const float*)d_in[4];
  const float* be1 = (const float*)d_in[5];
  const float* W2 = (const float*)d_in[6];
  const float* b2 = (const float*)d_in[7];
  const float* g2 = (const float*)d_in[8];
  const float* be2 = (const float*)d_in[9];
  const float* W3 = (const float*)d_in[10];
  const float* b3 = (const float*)d_in[11];
  const float* g3 = (const float*)d_in[12];
  const float* be3 = (const float*)d_in[13];

  char* ws = (char*)d_ws;
  // Layout / stream-ordered aliasing (r13/r14-verified):
  //   X3T   [0, 32MiB)            bf16 (B,2048t,2048c)
  //   Y12b  [32MiB, 56MiB)        bf16 (B,1536,2048) = GEMM1+2 output
  //   Y3p   [32MiB, 48MiB)        bf16 split-K partial pair (after normT12;
  //                               aliases dead Y12b — stream-ordered)
  //   partD [48MiB, +256KiB)      f64, dead before gemm12 writes Y12b
  //   featT [80MiB, 88MiB)        bf16 (B,2048,512); W3b aliases it after
  //                               gemm12 (featT dead; normT12 writes W3b)
  //   W12b  [88MiB, +1.5MiB)      bf16 stacked W1;W2
  //   small tail after W12b (cdf/raw1/raw2)
  u16*    X3T   = (u16*)(ws + 0);
  u16*    Y12b  = (u16*)(ws + 33554432);
  u16*    Y3p   = (u16*)(ws + 33554432);   // aliases dead Y12b
  double* partD = (double*)(ws + 50331648);
  u16*    featT = (u16*)(ws + 83886080);
  u16*    W3b   = (u16*)(ws + 83886080);   // aliases dead featT
  u16*    W12b  = (u16*)(ws + 92274688);
  int*    cdf   = (int*)(ws + 93847552);
  float*  raw1  = (float*)(ws + 93872128);
  float*  raw2  = (float*)(ws + 93873152);

  float* outMixed = (float*)d_out;                       // (B,512,2048) fp32
  float* outFeat  = outMixed + (size_t)4 * 512 * 2048;   // (B,1024,2048) fp32

  colmean_part_kernel<<<dim3(16, 8), 256, 0, stream>>>(frame, partD, raw1);
  scanD_kernel<<<1, 256, 0, stream>>>(partD, cdf);
  gatherTrans_kernel<<<dim3(8, 32, 11), 256, 0, stream>>>(frame, feature, cdf,
                                                          W1, W2, X3T, featT, W12b);
  gemm12_kernel<<<dim3(16, 24, 4), 128, 0, stream>>>(W12b, featT, b1, b2, Y12b,
                                                     raw1, raw2);
  normT12_kernel<<<dim3(32, 25, 4), 256, 0, stream>>>(Y12b, raw1, raw2,
                                                      g1, be1, g2, be2,
                                                      W3, W3b, X3T, outFeat);
  gemm3s_kernel<<<dim3(16, 8, 8), 128, 0, stream>>>(W3b, X3T, b3, Y3p);
  norm3g_kernel<<<dim3(32, 4), 1024, 0, stream>>>(Y3p, g3, be3, outMixed);
}